// Round 12
// baseline (442.930 us; speedup 1.0000x reference)
//
#include <hip/hip_runtime.h>
#include <hip/hip_bf16.h>

typedef _Float16 half_t;
typedef _Float16 f16x8 __attribute__((ext_vector_type(8)));
typedef _Float16 f16x4 __attribute__((ext_vector_type(4)));
typedef float f32x4 __attribute__((ext_vector_type(4)));
typedef float f32x16 __attribute__((ext_vector_type(16)));

#define B_ROWS 8192
#define D_DIM  1024

__device__ __forceinline__ void gload_lds16(const void* g, void* l)
{
    __builtin_amdgcn_global_load_lds((const __attribute__((address_space(1))) void*)g,
                                     (__attribute__((address_space(3))) void*)l, 16, 0, 0);
}

// ---------------------------------------------------------------------------
// f32 -> f16 convert
// ---------------------------------------------------------------------------
__global__ __launch_bounds__(256)
void cvt_f32_f16(const float* __restrict__ in, half_t* __restrict__ out, int n)
{
    int i = (blockIdx.x * 256 + threadIdx.x) * 4;
    int stride = gridDim.x * 256 * 4;
    for (; i < n; i += stride) {
        float4 v = *(const float4*)&in[i];
        f16x4 o;
        o[0] = (half_t)v.x; o[1] = (half_t)v.y; o[2] = (half_t)v.z; o[3] = (half_t)v.w;
        *(f16x4*)&out[i] = o;
    }
}

// ---------------------------------------------------------------------------
// LDS-tiled transpose (64x64 tiles, +1 pad)
// ---------------------------------------------------------------------------
__global__ __launch_bounds__(256)
void transpose_h(const half_t* __restrict__ in, half_t* __restrict__ out, int R, int C)
{
    __shared__ half_t t[64][65];
    int tilesC = C >> 6;
    int bc = blockIdx.x % tilesC;
    int br = blockIdx.x / tilesC;
    int r0 = br * 64, c0 = bc * 64;
    for (int e = threadIdx.x; e < 64 * 64; e += 256) {
        int r = e >> 6, c = e & 63;
        t[r][c] = in[(size_t)(r0 + r) * C + (c0 + c)];
    }
    __syncthreads();
    for (int e = threadIdx.x; e < 64 * 64; e += 256) {
        int r = e >> 6, c = e & 63;
        out[(size_t)(c0 + r) * R + (r0 + c)] = t[c][r];
    }
}

// ---------------------------------------------------------------------------
// 256x256 NT GEMM core (round-5 structure, measured ~875 TF), 32x32x16 MFMA.
//   raw[i,j] = scale * sum_k A[i,k]*B[j,k]
// 512 threads = 8 waves (2Mx4N). LDS 128 KiB (2 dbuf x 2 halves x A,B).
// 2-barrier 4-phase K-loop with B-frag dedup; one counted vmcnt(4)/K-tile.
// Swizzle: 16B-slot ^= (row&7) on read; inverse-swizzled global source.
// EPI: 0 = +aux[col] bias, f16 out                       (QKV projections)
//      3 = exp(raw-20) f16 out + per-block row partials -> aux2[zcol][row]
//          (LDS-scratch reduction, no shuffles/atomics)  (QK^T)
//      4 = atomicAdd f32 out of raw*aux[row]             (PV, aux = 1/Z)
// ---------------------------------------------------------------------------
template<int EPI>
__device__ __forceinline__ void gemm8_core(
    const half_t* __restrict__ A, const half_t* __restrict__ Bm,
    const float* __restrict__ aux, float* __restrict__ aux2, int zcol,
    void* __restrict__ Out,
    int lda, int ldb, int ldc, float scale,
    int row0, int col0, int ktile0, int nkt)
{
    __shared__ __align__(16) half_t smem[8 * 8192];   // As | Bs (and epilogue scratch)
    half_t* As = smem;
    half_t* Bs = smem + 4 * 8192;

    const int tid  = threadIdx.x;
    const int lane = tid & 63;
    const int wid  = tid >> 6;
    const int wr   = wid >> 2;     // 0..1  (M)
    const int wcn  = wid & 3;      // 0..3  (N)
    const int l31  = lane & 31;
    const int l32  = lane >> 5;

    // staging: linear LDS dest (tid*16), inverse-swizzled global source slot
    const int trow  = tid >> 3;                       // 0..63
    const int tslot = (tid & 7) ^ (trow & 7);
    const char* Apan[2] = { (const char*)(A + (size_t)row0 * lda),
                            (const char*)(A + (size_t)(row0 + 128) * lda) };
    const char* Bpan[2] = { (const char*)(Bm + (size_t)col0 * ldb),
                            (const char*)(Bm + (size_t)(col0 + 128) * ldb) };
    const size_t aoff[2] = { (size_t)trow * lda * 2 + (size_t)tslot * 16,
                             (size_t)(trow + 64) * lda * 2 + (size_t)tslot * 16 };
    const size_t boff[2] = { (size_t)trow * ldb * 2 + (size_t)tslot * 16,
                             (size_t)(trow + 64) * ldb * 2 + (size_t)tslot * 16 };
    const int dstb[2] = { tid * 16, 8192 + tid * 16 };

    auto stageA = [&](int h, int s, int buf) {
        char* d = (char*)(As + (buf * 2 + h) * 8192);
        const char* g = Apan[h] + (size_t)(ktile0 + s) * 128;
        gload_lds16(g + aoff[0], d + dstb[0]);
        gload_lds16(g + aoff[1], d + dstb[1]);
    };
    auto stageB = [&](int h, int s, int buf) {
        char* d = (char*)(Bs + (buf * 2 + h) * 8192);
        const char* g = Bpan[h] + (size_t)(ktile0 + s) * 128;
        gload_lds16(g + boff[0], d + dstb[0]);
        gload_lds16(g + boff[1], d + dstb[1]);
    };
    // swizzled fragment reads, 32x32 operand layout: row=lane&31, k=l32*8+j
    auto rdA = [&](int mm, int kc, const half_t* base) -> f16x8 {
        int rih  = wr * 64 + mm * 32 + l31;
        int byte = rih * 128 + (((kc * 2 + l32) ^ (rih & 7)) << 4);
        return *(const f16x8*)((const char*)base + byte);
    };
    auto rdB = [&](int kc, const half_t* base) -> f16x8 {
        int rih  = wcn * 32 + l31;
        int byte = rih * 128 + (((kc * 2 + l32) ^ (rih & 7)) << 4);
        return *(const f16x8*)((const char*)base + byte);
    };

    f32x16 acc[2][2][2] = {};   // [h][mm][nh]
    f16x8 af[2][4];             // A frags (current half), [mm][kc]
    f16x8 bfP[4], bfQ[4];       // B-half0 / B-half1 frags, [kc]

    // prologue: stage K-tile 0 fully + A0/B0 of tile 1; gate tile 0 (8 loads)
    {
        int s1 = (nkt > 1) ? 1 : 0;
        stageA(0, 0, 0); stageB(0, 0, 0); stageA(1, 0, 0); stageB(1, 0, 0);
        stageA(0, s1, 1); stageB(0, s1, 1);
    }
    asm volatile("s_waitcnt vmcnt(4)" ::: "memory");
    asm volatile("s_barrier" ::: "memory");

    for (int t = 0; t < nkt; ++t) {
        const int buf = t & 1;
        const half_t* A0 = As + (buf * 2 + 0) * 8192;
        const half_t* A1 = As + (buf * 2 + 1) * 8192;
        const half_t* B0 = Bs + (buf * 2 + 0) * 8192;
        const half_t* B1 = Bs + (buf * 2 + 1) * 8192;
        int t1  = t + 1; int t1s = (t1 < nkt) ? t1 : nkt - 1; int b1 = t1 & 1;
        int t2  = t + 2; int t2s = (t2 < nkt) ? t2 : nkt - 1;

        // ---- phase 1: (A-half0, B-half0) -> acc[0][*][0]
        #pragma unroll
        for (int mm = 0; mm < 2; ++mm)
            #pragma unroll
            for (int kc = 0; kc < 4; ++kc) af[mm][kc] = rdA(mm, kc, A0);
        #pragma unroll
        for (int kc = 0; kc < 4; ++kc) bfP[kc] = rdB(kc, B0);
        stageA(1, t1s, b1);
        asm volatile("s_barrier" ::: "memory");
        __builtin_amdgcn_s_setprio(1);
        #pragma unroll
        for (int kc = 0; kc < 4; ++kc)
            #pragma unroll
            for (int mm = 0; mm < 2; ++mm)
                acc[0][mm][0] = __builtin_amdgcn_mfma_f32_32x32x16_f16(af[mm][kc], bfP[kc], acc[0][mm][0], 0, 0, 0);
        __builtin_amdgcn_s_setprio(0);
        asm volatile("s_barrier" ::: "memory");

        // ---- phase 2: (A-half0, B-half1) -> acc[0][*][1]
        #pragma unroll
        for (int kc = 0; kc < 4; ++kc) bfQ[kc] = rdB(kc, B1);
        stageB(1, t1s, b1);
        asm volatile("s_barrier" ::: "memory");
        __builtin_amdgcn_s_setprio(1);
        #pragma unroll
        for (int kc = 0; kc < 4; ++kc)
            #pragma unroll
            for (int mm = 0; mm < 2; ++mm)
                acc[0][mm][1] = __builtin_amdgcn_mfma_f32_32x32x16_f16(af[mm][kc], bfQ[kc], acc[0][mm][1], 0, 0, 0);
        __builtin_amdgcn_s_setprio(0);
        asm volatile("s_barrier" ::: "memory");

        // ---- phase 3: (A-half1, B-half0) -> acc[1][*][0]  (af overwritten, bfP reused)
        #pragma unroll
        for (int mm = 0; mm < 2; ++mm)
            #pragma unroll
            for (int kc = 0; kc < 4; ++kc) af[mm][kc] = rdA(mm, kc, A1);
        stageA(0, t2s, buf);
        asm volatile("s_barrier" ::: "memory");
        __builtin_amdgcn_s_setprio(1);
        #pragma unroll
        for (int kc = 0; kc < 4; ++kc)
            #pragma unroll
            for (int mm = 0; mm < 2; ++mm)
                acc[1][mm][0] = __builtin_amdgcn_mfma_f32_32x32x16_f16(af[mm][kc], bfP[kc], acc[1][mm][0], 0, 0, 0);
        __builtin_amdgcn_s_setprio(0);
        asm volatile("s_barrier" ::: "memory");

        // ---- phase 4: (A-half1, B-half1) -> acc[1][*][1]  (no reads)
        stageB(0, t2s, buf);
        asm volatile("s_barrier" ::: "memory");
        __builtin_amdgcn_s_setprio(1);
        #pragma unroll
        for (int kc = 0; kc < 4; ++kc)
            #pragma unroll
            for (int mm = 0; mm < 2; ++mm)
                acc[1][mm][1] = __builtin_amdgcn_mfma_f32_32x32x16_f16(af[mm][kc], bfQ[kc], acc[1][mm][1], 0, 0, 0);
        __builtin_amdgcn_s_setprio(0);
        asm volatile("s_waitcnt vmcnt(4)" ::: "memory");   // counted gate: next tile landed
        asm volatile("s_barrier" ::: "memory");
    }

    // epilogue: 32x32 C/D layout: col = lane&31, row = (g&3) + 8*(g>>2) + 4*l32
    if (EPI == 3) {
        // exp-space E stores + per-block row sums via LDS scratch (smem is
        // reusable after draining the trailing stage loads).
        asm volatile("s_waitcnt vmcnt(0)" ::: "memory");
        asm volatile("s_barrier" ::: "memory");
        half_t* scratch = smem;                    // [256][136] f16 = 69.6 KB
        const int contrib = wcn * 32 + l31;
        #pragma unroll
        for (int h = 0; h < 2; ++h) {
            #pragma unroll
            for (int mm = 0; mm < 2; ++mm) {
                int rl0 = h * 128 + wr * 64 + mm * 32 + 4 * l32;
                #pragma unroll
                for (int g = 0; g < 16; ++g) {
                    int rl = rl0 + (g & 3) + 8 * (g >> 2);
                    float rs = 0.0f;
                    #pragma unroll
                    for (int nh = 0; nh < 2; ++nh) {
                        int gcol = col0 + nh * 128 + wcn * 32 + l31;
                        float e = __expf(acc[h][mm][nh][g] * scale - 20.0f);
                        rs += e;
                        ((half_t*)Out)[(size_t)(row0 + rl) * ldc + gcol] = (half_t)e;
                    }
                    scratch[rl * 136 + contrib] = (half_t)rs;
                }
            }
        }
        asm volatile("s_waitcnt lgkmcnt(0)" ::: "memory");
        asm volatile("s_barrier" ::: "memory");
        {
            int row  = tid >> 1;
            int half = tid & 1;
            const half_t* src = scratch + row * 136 + half * 64;
            float s = 0.0f;
            #pragma unroll
            for (int j = 0; j < 8; ++j) {
                f16x8 v = *(const f16x8*)&src[j * 8];
                #pragma unroll
                for (int tt = 0; tt < 8; ++tt) s += (float)v[tt];
            }
            s += __shfl_xor(s, 1);
            if (half == 0) aux2[(size_t)zcol * B_ROWS + row0 + row] = s;
        }
    } else {
        #pragma unroll
        for (int h = 0; h < 2; ++h) {
            #pragma unroll
            for (int mm = 0; mm < 2; ++mm) {
                int r0 = row0 + h * 128 + wr * 64 + mm * 32 + 4 * l32;
                #pragma unroll
                for (int nh = 0; nh < 2; ++nh) {
                    int gcol = col0 + nh * 128 + wcn * 32 + l31;
                    float badd = (EPI == 0) ? aux[gcol] : 0.0f;
                    #pragma unroll
                    for (int g = 0; g < 16; ++g) {
                        int row = r0 + (g & 3) + 8 * (g >> 2);
                        float v = acc[h][mm][nh][g] * scale + badd;
                        size_t idx = (size_t)row * ldc + gcol;
                        if (EPI == 4)      atomicAdd(&((float*)Out)[idx], v * aux[row]);
                        else               ((half_t*)Out)[idx] = (half_t)v;
                    }
                }
            }
        }
    }
}

// wrapper. REMAP=1: 16x16 supertile + XCD-chunked 2x16 slabs (requires 32x32 grid).
// REMAP=0: plain XCD swizzle. zcol (for EPI=3 partial sums) = bx.
template<int EPI, int REMAP>
__global__ __launch_bounds__(512, 2)
void gemm8(const half_t* __restrict__ A, const half_t* __restrict__ Bm,
           const float* __restrict__ aux, float* __restrict__ aux2,
           void* __restrict__ Out,
           int lda, int ldb, int ldc, float scale, int nkt)
{
    int bx, by;
    if (REMAP) {
        int L = blockIdx.y * gridDim.x + blockIdx.x;   // 0..1023
        int s = L >> 8;            // supertile 0..3 (2x2 of 16x16)
        int u = L & 255;
        int xcd  = u & 7;
        int slot = u >> 3;         // 0..31 within XCD: 2 rows x 16 cols
        by = (s >> 1) * 16 + xcd * 2 + (slot >> 4);
        bx = (s & 1) * 16 + (slot & 15);
    } else {
        int nwg = gridDim.x * gridDim.y;
        int bid = blockIdx.y * gridDim.x + blockIdx.x;
        if ((nwg & 7) == 0) { int c = nwg >> 3; bid = (bid & 7) * c + (bid >> 3); }
        bx = bid % gridDim.x; by = bid / gridDim.x;
    }
    gemm8_core<EPI>(A, Bm, aux, aux2, bx, Out, lda, ldb, ldc, scale,
                    by * 256, bx * 256, 0, nkt);
}

// fused QKV projections: z picks (W, b, Out)  [r4 mapping: direct blockIdx]
__global__ __launch_bounds__(512, 2)
void gemm8_qkv(const half_t* __restrict__ xh,
               const half_t* __restrict__ Wq, const half_t* __restrict__ Wk, const half_t* __restrict__ Wv,
               const float* __restrict__ bq, const float* __restrict__ bk, const float* __restrict__ bv,
               half_t* __restrict__ Q, half_t* __restrict__ K, half_t* __restrict__ V)
{
    int z = blockIdx.z;
    const half_t* W = (z == 0) ? Wq : (z == 1) ? Wk : Wv;
    const float*  b = (z == 0) ? bq : (z == 1) ? bk : bv;
    half_t*       O = (z == 0) ? Q  : (z == 1) ? K  : V;
    gemm8_core<0>(xh, W, b, nullptr, 0, O, D_DIM, D_DIM, D_DIM, 1.0f,
                  blockIdx.y * 256, blockIdx.x * 256, 0, D_DIM / 64);
}

// PV, split-K=2 [r4 mapping], both halves atomicAdd (E V^T)*Zinv[row] into out
__global__ __launch_bounds__(512, 2)
void gemm8_pv(const half_t* __restrict__ E, const half_t* __restrict__ Vt,
              const float* __restrict__ Zinv, float* __restrict__ out)
{
    int z = blockIdx.z;
    gemm8_core<4>(E, Vt, Zinv, nullptr, 0, out, B_ROWS, B_ROWS, D_DIM, 1.0f,
                  blockIdx.y * 256, blockIdx.x * 256, z * (B_ROWS / 128), B_ROWS / 128);
}

// Zinv[r] = 1 / sum_c Zpart[c][r]   (32 col-block partials per row)
__global__ __launch_bounds__(256)
void zreduce(const float* __restrict__ Zpart, float* __restrict__ Zinv, int nrow)
{
    int r = blockIdx.x * 256 + threadIdx.x;
    float s = 0.0f;
    #pragma unroll
    for (int c = 0; c < 32; ++c) s += Zpart[(size_t)c * nrow + r];
    Zinv[r] = 1.0f / s;
}

// ---------------------------------------------------------------------------
// launcher
// ---------------------------------------------------------------------------
extern "C" void kernel_launch(void* const* d_in, const int* in_sizes, int n_in,
                              void* d_out, int out_size, void* d_ws, size_t ws_size,
                              hipStream_t stream)
{
    const float* x  = (const float*)d_in[0];
    const float* Wq = (const float*)d_in[1];
    const float* bq = (const float*)d_in[2];
    const float* Wk = (const float*)d_in[3];
    const float* bk = (const float*)d_in[4];
    const float* Wv = (const float*)d_in[5];
    const float* bv = (const float*)d_in[6];
    float* out = (float*)d_out;

    const int Bb = B_ROWS, Dd = D_DIM;

    char* w = (char*)d_ws;
    size_t off = 0;
    auto carve = [&](size_t bytes) {
        void* p = w + off;
        off += (bytes + 255) & ~(size_t)255;
        return p;
    };
    half_t* xh  = (half_t*)carve((size_t)Bb * Dd * 2);
    half_t* Wqh = (half_t*)carve((size_t)Dd * Dd * 2);
    half_t* Wkh = (half_t*)carve((size_t)Dd * Dd * 2);
    half_t* Wvh = (half_t*)carve((size_t)Dd * Dd * 2);
    half_t* Qh  = (half_t*)carve((size_t)Bb * Dd * 2);
    half_t* Kh  = (half_t*)carve((size_t)Bb * Dd * 2);
    half_t* Vh  = (half_t*)carve((size_t)Bb * Dd * 2);
    half_t* S   = (half_t*)carve((size_t)Bb * Bb * 2);   // exp-space E
    float*  Zp  = (float*)carve((size_t)32 * Bb * 4);     // per-colblock row sums
    float*  Z   = (float*)carve((size_t)Bb * 4);          // 1/rowsum
    half_t* Vt  = xh;                 // xh dead after projections

    // 1) converts + zero the atomic output accumulator
    cvt_f32_f16<<<2048, 256, 0, stream>>>(x,  xh,  Bb * Dd);
    cvt_f32_f16<<<1024, 256, 0, stream>>>(Wq, Wqh, Dd * Dd);
    cvt_f32_f16<<<1024, 256, 0, stream>>>(Wk, Wkh, Dd * Dd);
    cvt_f32_f16<<<1024, 256, 0, stream>>>(Wv, Wvh, Dd * Dd);
    hipMemsetAsync(out, 0, (size_t)Bb * Dd * 4, stream);

    // 2) fused QKV projections
    dim3 gqkv(Dd / 256, Bb / 256, 3);
    gemm8_qkv<<<gqkv, 512, 0, stream>>>(xh, Wqh, Wkh, Wvh, bq, bk, bv, Qh, Kh, Vh);

    // 3) V -> V^T
    transpose_h<<<(Dd / 64) * (Bb / 64), 256, 0, stream>>>(Vh, Vt, Bb, Dd);

    // 4) E = exp(0.125*Q K^T - 20) + per-block row partials -> Zp  (supertile remap)
    dim3 gs(Bb / 256, Bb / 256);
    gemm8<3, 1><<<gs, 512, 0, stream>>>(Qh, Kh, nullptr, Zp, S, Dd, Dd, Bb, 0.125f, Dd / 64);

    // 5) Zinv = 1 / rowsum  (1 MB reduce)
    zreduce<<<Bb / 256, 256, 0, stream>>>(Zp, Z, Bb);

    // 6) out += (E Vt^T) * Zinv[row]  (split-K=2, atomic, memset-initialized)
    dim3 gpv(Dd / 256, Bb / 256, 2);
    gemm8_pv<<<gpv, 512, 0, stream>>>(S, Vt, Z, out);
}

// Round 13
// 415.988 us; speedup vs baseline: 1.0648x; 1.0648x over previous
//
#include <hip/hip_runtime.h>
#include <hip/hip_bf16.h>

typedef _Float16 half_t;
typedef _Float16 f16x8 __attribute__((ext_vector_type(8)));
typedef _Float16 f16x4 __attribute__((ext_vector_type(4)));
typedef float f32x4 __attribute__((ext_vector_type(4)));
typedef float f32x16 __attribute__((ext_vector_type(16)));

#define B_ROWS 8192
#define D_DIM  1024

__device__ __forceinline__ void gload_lds16(const void* g, void* l)
{
    __builtin_amdgcn_global_load_lds((const __attribute__((address_space(1))) void*)g,
                                     (__attribute__((address_space(3))) void*)l, 16, 0, 0);
}

// ---------------------------------------------------------------------------
// f32 -> f16 convert
// ---------------------------------------------------------------------------
__global__ __launch_bounds__(256)
void cvt_f32_f16(const float* __restrict__ in, half_t* __restrict__ out, int n)
{
    int i = (blockIdx.x * 256 + threadIdx.x) * 4;
    int stride = gridDim.x * 256 * 4;
    for (; i < n; i += stride) {
        float4 v = *(const float4*)&in[i];
        f16x4 o;
        o[0] = (half_t)v.x; o[1] = (half_t)v.y; o[2] = (half_t)v.z; o[3] = (half_t)v.w;
        *(f16x4*)&out[i] = o;
    }
}

// ---------------------------------------------------------------------------
// LDS-tiled transpose (64x64 tiles, +1 pad)
// ---------------------------------------------------------------------------
__global__ __launch_bounds__(256)
void transpose_h(const half_t* __restrict__ in, half_t* __restrict__ out, int R, int C)
{
    __shared__ half_t t[64][65];
    int tilesC = C >> 6;
    int bc = blockIdx.x % tilesC;
    int br = blockIdx.x / tilesC;
    int r0 = br * 64, c0 = bc * 64;
    for (int e = threadIdx.x; e < 64 * 64; e += 256) {
        int r = e >> 6, c = e & 63;
        t[r][c] = in[(size_t)(r0 + r) * C + (c0 + c)];
    }
    __syncthreads();
    for (int e = threadIdx.x; e < 64 * 64; e += 256) {
        int r = e >> 6, c = e & 63;
        out[(size_t)(c0 + r) * R + (r0 + c)] = t[c][r];
    }
}

// ---------------------------------------------------------------------------
// 256x256 NT GEMM core (round-5 structure, measured ~875 TF), 32x32x16 MFMA.
//   raw[i,j] = scale * sum_k A[i,k]*B[j,k]
// 512 threads = 8 waves (2Mx4N). LDS 128 KiB (2 dbuf x 2 halves x A,B).
// 2-barrier 4-phase K-loop with B-frag dedup; one counted vmcnt(4)/K-tile.
// Swizzle: 16B-slot ^= (row&7) on read; inverse-swizzled global source.
// EPI: 0 = +aux[col] bias, f16 out                       (QKV projections)
//      3 = exp(raw-20) f16 out + per-block row partials -> aux2[zcol][row]
//          (LDS-scratch reduction, no shuffles/atomics)  (QK^T)
//      4 = f32 out of raw*aux[row]                       (PV, aux = 1/Z)
// ---------------------------------------------------------------------------
template<int EPI>
__device__ __forceinline__ void gemm8_core(
    const half_t* __restrict__ A, const half_t* __restrict__ Bm,
    const float* __restrict__ aux, float* __restrict__ aux2, int zcol,
    void* __restrict__ Out,
    int lda, int ldb, int ldc, float scale,
    int row0, int col0, int ktile0, int nkt)
{
    __shared__ __align__(16) half_t smem[8 * 8192];   // As | Bs (and epilogue scratch)
    half_t* As = smem;
    half_t* Bs = smem + 4 * 8192;

    const int tid  = threadIdx.x;
    const int lane = tid & 63;
    const int wid  = tid >> 6;
    const int wr   = wid >> 2;     // 0..1  (M)
    const int wcn  = wid & 3;      // 0..3  (N)
    const int l31  = lane & 31;
    const int l32  = lane >> 5;

    // staging: linear LDS dest (tid*16), inverse-swizzled global source slot
    const int trow  = tid >> 3;                       // 0..63
    const int tslot = (tid & 7) ^ (trow & 7);
    const char* Apan[2] = { (const char*)(A + (size_t)row0 * lda),
                            (const char*)(A + (size_t)(row0 + 128) * lda) };
    const char* Bpan[2] = { (const char*)(Bm + (size_t)col0 * ldb),
                            (const char*)(Bm + (size_t)(col0 + 128) * ldb) };
    const size_t aoff[2] = { (size_t)trow * lda * 2 + (size_t)tslot * 16,
                             (size_t)(trow + 64) * lda * 2 + (size_t)tslot * 16 };
    const size_t boff[2] = { (size_t)trow * ldb * 2 + (size_t)tslot * 16,
                             (size_t)(trow + 64) * ldb * 2 + (size_t)tslot * 16 };
    const int dstb[2] = { tid * 16, 8192 + tid * 16 };

    auto stageA = [&](int h, int s, int buf) {
        char* d = (char*)(As + (buf * 2 + h) * 8192);
        const char* g = Apan[h] + (size_t)(ktile0 + s) * 128;
        gload_lds16(g + aoff[0], d + dstb[0]);
        gload_lds16(g + aoff[1], d + dstb[1]);
    };
    auto stageB = [&](int h, int s, int buf) {
        char* d = (char*)(Bs + (buf * 2 + h) * 8192);
        const char* g = Bpan[h] + (size_t)(ktile0 + s) * 128;
        gload_lds16(g + boff[0], d + dstb[0]);
        gload_lds16(g + boff[1], d + dstb[1]);
    };
    // swizzled fragment reads, 32x32 operand layout: row=lane&31, k=l32*8+j
    auto rdA = [&](int mm, int kc, const half_t* base) -> f16x8 {
        int rih  = wr * 64 + mm * 32 + l31;
        int byte = rih * 128 + (((kc * 2 + l32) ^ (rih & 7)) << 4);
        return *(const f16x8*)((const char*)base + byte);
    };
    auto rdB = [&](int kc, const half_t* base) -> f16x8 {
        int rih  = wcn * 32 + l31;
        int byte = rih * 128 + (((kc * 2 + l32) ^ (rih & 7)) << 4);
        return *(const f16x8*)((const char*)base + byte);
    };

    f32x16 acc[2][2][2] = {};   // [h][mm][nh]
    f16x8 af[2][4];             // A frags (current half), [mm][kc]
    f16x8 bfP[4], bfQ[4];       // B-half0 / B-half1 frags, [kc]

    // prologue: stage K-tile 0 fully + A0/B0 of tile 1; gate tile 0 (8 loads)
    {
        int s1 = (nkt > 1) ? 1 : 0;
        stageA(0, 0, 0); stageB(0, 0, 0); stageA(1, 0, 0); stageB(1, 0, 0);
        stageA(0, s1, 1); stageB(0, s1, 1);
    }
    asm volatile("s_waitcnt vmcnt(4)" ::: "memory");
    asm volatile("s_barrier" ::: "memory");

    for (int t = 0; t < nkt; ++t) {
        const int buf = t & 1;
        const half_t* A0 = As + (buf * 2 + 0) * 8192;
        const half_t* A1 = As + (buf * 2 + 1) * 8192;
        const half_t* B0 = Bs + (buf * 2 + 0) * 8192;
        const half_t* B1 = Bs + (buf * 2 + 1) * 8192;
        int t1  = t + 1; int t1s = (t1 < nkt) ? t1 : nkt - 1; int b1 = t1 & 1;
        int t2  = t + 2; int t2s = (t2 < nkt) ? t2 : nkt - 1;

        // ---- phase 1: (A-half0, B-half0) -> acc[0][*][0]
        #pragma unroll
        for (int mm = 0; mm < 2; ++mm)
            #pragma unroll
            for (int kc = 0; kc < 4; ++kc) af[mm][kc] = rdA(mm, kc, A0);
        #pragma unroll
        for (int kc = 0; kc < 4; ++kc) bfP[kc] = rdB(kc, B0);
        stageA(1, t1s, b1);
        asm volatile("s_barrier" ::: "memory");
        __builtin_amdgcn_s_setprio(1);
        #pragma unroll
        for (int kc = 0; kc < 4; ++kc)
            #pragma unroll
            for (int mm = 0; mm < 2; ++mm)
                acc[0][mm][0] = __builtin_amdgcn_mfma_f32_32x32x16_f16(af[mm][kc], bfP[kc], acc[0][mm][0], 0, 0, 0);
        __builtin_amdgcn_s_setprio(0);
        asm volatile("s_barrier" ::: "memory");

        // ---- phase 2: (A-half0, B-half1) -> acc[0][*][1]
        #pragma unroll
        for (int kc = 0; kc < 4; ++kc) bfQ[kc] = rdB(kc, B1);
        stageB(1, t1s, b1);
        asm volatile("s_barrier" ::: "memory");
        __builtin_amdgcn_s_setprio(1);
        #pragma unroll
        for (int kc = 0; kc < 4; ++kc)
            #pragma unroll
            for (int mm = 0; mm < 2; ++mm)
                acc[0][mm][1] = __builtin_amdgcn_mfma_f32_32x32x16_f16(af[mm][kc], bfQ[kc], acc[0][mm][1], 0, 0, 0);
        __builtin_amdgcn_s_setprio(0);
        asm volatile("s_barrier" ::: "memory");

        // ---- phase 3: (A-half1, B-half0) -> acc[1][*][0]  (af overwritten, bfP reused)
        #pragma unroll
        for (int mm = 0; mm < 2; ++mm)
            #pragma unroll
            for (int kc = 0; kc < 4; ++kc) af[mm][kc] = rdA(mm, kc, A1);
        stageA(0, t2s, buf);
        asm volatile("s_barrier" ::: "memory");
        __builtin_amdgcn_s_setprio(1);
        #pragma unroll
        for (int kc = 0; kc < 4; ++kc)
            #pragma unroll
            for (int mm = 0; mm < 2; ++mm)
                acc[1][mm][0] = __builtin_amdgcn_mfma_f32_32x32x16_f16(af[mm][kc], bfP[kc], acc[1][mm][0], 0, 0, 0);
        __builtin_amdgcn_s_setprio(0);
        asm volatile("s_barrier" ::: "memory");

        // ---- phase 4: (A-half1, B-half1) -> acc[1][*][1]  (no reads)
        stageB(0, t2s, buf);
        asm volatile("s_barrier" ::: "memory");
        __builtin_amdgcn_s_setprio(1);
        #pragma unroll
        for (int kc = 0; kc < 4; ++kc)
            #pragma unroll
            for (int mm = 0; mm < 2; ++mm)
                acc[1][mm][1] = __builtin_amdgcn_mfma_f32_32x32x16_f16(af[mm][kc], bfQ[kc], acc[1][mm][1], 0, 0, 0);
        __builtin_amdgcn_s_setprio(0);
        asm volatile("s_waitcnt vmcnt(4)" ::: "memory");   // counted gate: next tile landed
        asm volatile("s_barrier" ::: "memory");
    }

    // epilogue: 32x32 C/D layout: col = lane&31, row = (g&3) + 8*(g>>2) + 4*l32
    if (EPI == 3) {
        // exp-space E stores + per-block row sums via LDS scratch (smem is
        // reusable after draining the trailing stage loads).
        asm volatile("s_waitcnt vmcnt(0)" ::: "memory");
        asm volatile("s_barrier" ::: "memory");
        half_t* scratch = smem;                    // [256][136] f16 = 69.6 KB
        const int contrib = wcn * 32 + l31;
        #pragma unroll
        for (int h = 0; h < 2; ++h) {
            #pragma unroll
            for (int mm = 0; mm < 2; ++mm) {
                int rl0 = h * 128 + wr * 64 + mm * 32 + 4 * l32;
                #pragma unroll
                for (int g = 0; g < 16; ++g) {
                    int rl = rl0 + (g & 3) + 8 * (g >> 2);
                    float rs = 0.0f;
                    #pragma unroll
                    for (int nh = 0; nh < 2; ++nh) {
                        int gcol = col0 + nh * 128 + wcn * 32 + l31;
                        float e = __expf(acc[h][mm][nh][g] * scale - 20.0f);
                        rs += e;
                        ((half_t*)Out)[(size_t)(row0 + rl) * ldc + gcol] = (half_t)e;
                    }
                    scratch[rl * 136 + contrib] = (half_t)rs;
                }
            }
        }
        asm volatile("s_waitcnt lgkmcnt(0)" ::: "memory");
        asm volatile("s_barrier" ::: "memory");
        {
            int row  = tid >> 1;
            int half = tid & 1;
            const half_t* src = scratch + row * 136 + half * 64;
            float s = 0.0f;
            #pragma unroll
            for (int j = 0; j < 8; ++j) {
                f16x8 v = *(const f16x8*)&src[j * 8];
                #pragma unroll
                for (int tt = 0; tt < 8; ++tt) s += (float)v[tt];
            }
            s += __shfl_xor(s, 1);
            if (half == 0) aux2[(size_t)zcol * B_ROWS + row0 + row] = s;
        }
    } else {
        #pragma unroll
        for (int h = 0; h < 2; ++h) {
            #pragma unroll
            for (int mm = 0; mm < 2; ++mm) {
                int r0 = row0 + h * 128 + wr * 64 + mm * 32 + 4 * l32;
                #pragma unroll
                for (int nh = 0; nh < 2; ++nh) {
                    int gcol = col0 + nh * 128 + wcn * 32 + l31;
                    float badd = (EPI == 0) ? aux[gcol] : 0.0f;
                    #pragma unroll
                    for (int g = 0; g < 16; ++g) {
                        int row = r0 + (g & 3) + 8 * (g >> 2);
                        float v = acc[h][mm][nh][g] * scale + badd;
                        size_t idx = (size_t)row * ldc + gcol;
                        if (EPI == 4)      ((float*)Out)[idx] = v * aux[row];
                        else               ((half_t*)Out)[idx] = (half_t)v;
                    }
                }
            }
        }
    }
}

// wrapper. REMAP=1: 16x16 supertile + XCD-chunked 2x16 slabs (requires 32x32 grid).
// REMAP=0: plain XCD swizzle. zcol (for EPI=3 partial sums) = bx.
template<int EPI, int REMAP>
__global__ __launch_bounds__(512, 2)
void gemm8(const half_t* __restrict__ A, const half_t* __restrict__ Bm,
           const float* __restrict__ aux, float* __restrict__ aux2,
           void* __restrict__ Out,
           int lda, int ldb, int ldc, float scale, int nkt)
{
    int bx, by;
    if (REMAP) {
        int L = blockIdx.y * gridDim.x + blockIdx.x;   // 0..1023
        int s = L >> 8;            // supertile 0..3 (2x2 of 16x16)
        int u = L & 255;
        int xcd  = u & 7;
        int slot = u >> 3;         // 0..31 within XCD: 2 rows x 16 cols
        by = (s >> 1) * 16 + xcd * 2 + (slot >> 4);
        bx = (s & 1) * 16 + (slot & 15);
    } else {
        int nwg = gridDim.x * gridDim.y;
        int bid = blockIdx.y * gridDim.x + blockIdx.x;
        if ((nwg & 7) == 0) { int c = nwg >> 3; bid = (bid & 7) * c + (bid >> 3); }
        bx = bid % gridDim.x; by = bid / gridDim.x;
    }
    gemm8_core<EPI>(A, Bm, aux, aux2, bx, Out, lda, ldb, ldc, scale,
                    by * 256, bx * 256, 0, nkt);
}

// fused QKV projections: z picks (W, b, Out)  [r4 mapping: direct blockIdx]
__global__ __launch_bounds__(512, 2)
void gemm8_qkv(const half_t* __restrict__ xh,
               const half_t* __restrict__ Wq, const half_t* __restrict__ Wk, const half_t* __restrict__ Wv,
               const float* __restrict__ bq, const float* __restrict__ bk, const float* __restrict__ bv,
               half_t* __restrict__ Q, half_t* __restrict__ K, half_t* __restrict__ V)
{
    int z = blockIdx.z;
    const half_t* W = (z == 0) ? Wq : (z == 1) ? Wk : Wv;
    const float*  b = (z == 0) ? bq : (z == 1) ? bk : bv;
    half_t*       O = (z == 0) ? Q  : (z == 1) ? K  : V;
    gemm8_core<0>(xh, W, b, nullptr, 0, O, D_DIM, D_DIM, D_DIM, 1.0f,
                  blockIdx.y * 256, blockIdx.x * 256, 0, D_DIM / 64);
}

// PV with split-K=2 [r4 mapping], plain stores of (E V^T)*Zinv[row] into
// part0 (=out) / part1; reduced by add_f32 afterwards.
__global__ __launch_bounds__(512, 2)
void gemm8_pv(const half_t* __restrict__ E, const half_t* __restrict__ Vt,
              const float* __restrict__ Zinv,
              float* __restrict__ part0, float* __restrict__ part1)
{
    int z = blockIdx.z;
    float* O = z ? part1 : part0;
    gemm8_core<4>(E, Vt, Zinv, nullptr, 0, O, B_ROWS, B_ROWS, D_DIM, 1.0f,
                  blockIdx.y * 256, blockIdx.x * 256, z * (B_ROWS / 128), B_ROWS / 128);
}

// Zinv[r] = 1 / sum_c Zpart[c][r]   (32 col-block partials per row)
__global__ __launch_bounds__(256)
void zreduce(const float* __restrict__ Zpart, float* __restrict__ Zinv, int nrow)
{
    int r = blockIdx.x * 256 + threadIdx.x;
    float s = 0.0f;
    #pragma unroll
    for (int c = 0; c < 32; ++c) s += Zpart[(size_t)c * nrow + r];
    Zinv[r] = 1.0f / s;
}

// out += a
__global__ __launch_bounds__(256)
void add_f32(const float* __restrict__ a, float* __restrict__ out, int n)
{
    int i = (blockIdx.x * 256 + threadIdx.x) * 4;
    int stride = gridDim.x * 256 * 4;
    for (; i < n; i += stride) {
        float4 x = *(const float4*)&out[i];
        float4 y = *(const float4*)&a[i];
        x.x += y.x; x.y += y.y; x.z += y.z; x.w += y.w;
        *(float4*)&out[i] = x;
    }
}

// ---------------------------------------------------------------------------
// launcher
// ---------------------------------------------------------------------------
extern "C" void kernel_launch(void* const* d_in, const int* in_sizes, int n_in,
                              void* d_out, int out_size, void* d_ws, size_t ws_size,
                              hipStream_t stream)
{
    const float* x  = (const float*)d_in[0];
    const float* Wq = (const float*)d_in[1];
    const float* bq = (const float*)d_in[2];
    const float* Wk = (const float*)d_in[3];
    const float* bk = (const float*)d_in[4];
    const float* Wv = (const float*)d_in[5];
    const float* bv = (const float*)d_in[6];
    float* out = (float*)d_out;

    const int Bb = B_ROWS, Dd = D_DIM;

    char* w = (char*)d_ws;
    size_t off = 0;
    auto carve = [&](size_t bytes) {
        void* p = w + off;
        off += (bytes + 255) & ~(size_t)255;
        return p;
    };
    half_t* xh  = (half_t*)carve((size_t)Bb * Dd * 2);
    half_t* Wqh = (half_t*)carve((size_t)Dd * Dd * 2);
    half_t* Wkh = (half_t*)carve((size_t)Dd * Dd * 2);
    half_t* Wvh = (half_t*)carve((size_t)Dd * Dd * 2);
    half_t* Qh  = (half_t*)carve((size_t)Bb * Dd * 2);
    half_t* Kh  = (half_t*)carve((size_t)Bb * Dd * 2);
    half_t* Vh  = (half_t*)carve((size_t)Bb * Dd * 2);
    half_t* S   = (half_t*)carve((size_t)Bb * Bb * 2);   // exp-space E
    float*  Zp  = (float*)carve((size_t)32 * Bb * 4);     // per-colblock row sums
    float*  Z   = (float*)carve((size_t)Bb * 4);          // 1/rowsum
    half_t* Vt  = xh;                 // xh dead after projections
    float*  part1 = (float*)Qh;       // Qh+Kh dead after QK^T

    // 1) converts
    cvt_f32_f16<<<2048, 256, 0, stream>>>(x,  xh,  Bb * Dd);
    cvt_f32_f16<<<1024, 256, 0, stream>>>(Wq, Wqh, Dd * Dd);
    cvt_f32_f16<<<1024, 256, 0, stream>>>(Wk, Wkh, Dd * Dd);
    cvt_f32_f16<<<1024, 256, 0, stream>>>(Wv, Wvh, Dd * Dd);

    // 2) fused QKV projections
    dim3 gqkv(Dd / 256, Bb / 256, 3);
    gemm8_qkv<<<gqkv, 512, 0, stream>>>(xh, Wqh, Wkh, Wvh, bq, bk, bv, Qh, Kh, Vh);

    // 3) V -> V^T
    transpose_h<<<(Dd / 64) * (Bb / 64), 256, 0, stream>>>(Vh, Vt, Bb, Dd);

    // 4) E = exp(0.125*Q K^T - 20) + per-block row partials -> Zp  (supertile remap)
    dim3 gs(Bb / 256, Bb / 256);
    gemm8<3, 1><<<gs, 512, 0, stream>>>(Qh, Kh, nullptr, Zp, S, Dd, Dd, Bb, 0.125f, Dd / 64);

    // 5) Zinv = 1 / rowsum  (1 MB reduce)
    zreduce<<<Bb / 256, 256, 0, stream>>>(Zp, Z, Bb);

    // 6) O = (E Vt^T) * Zinv[row], split-K=2 (plain stores), then reduce partials
    dim3 gpv(Dd / 256, Bb / 256, 2);
    gemm8_pv<<<gpv, 512, 0, stream>>>(S, Vt, Z, out, part1);
    add_f32<<<2048, 256, 0, stream>>>(part1, out, Bb * Dd);
}

// Round 14
// 410.480 us; speedup vs baseline: 1.0791x; 1.0134x over previous
//
#include <hip/hip_runtime.h>
#include <hip/hip_bf16.h>

typedef _Float16 half_t;
typedef _Float16 f16x8 __attribute__((ext_vector_type(8)));
typedef _Float16 f16x4 __attribute__((ext_vector_type(4)));
typedef float f32x4 __attribute__((ext_vector_type(4)));
typedef float f32x16 __attribute__((ext_vector_type(16)));

#define B_ROWS 8192
#define D_DIM  1024

__device__ __forceinline__ void gload_lds16(const void* g, void* l)
{
    __builtin_amdgcn_global_load_lds((const __attribute__((address_space(1))) void*)g,
                                     (__attribute__((address_space(3))) void*)l, 16, 0, 0);
}

// ---------------------------------------------------------------------------
// merged f32 -> f16 convert for x, Wq, Wk, Wv (one dispatch)
// ---------------------------------------------------------------------------
__global__ __launch_bounds__(256)
void cvt_all(const float* __restrict__ x,  const float* __restrict__ Wq,
             const float* __restrict__ Wk, const float* __restrict__ Wv,
             half_t* __restrict__ xh,  half_t* __restrict__ Wqh,
             half_t* __restrict__ Wkh, half_t* __restrict__ Wvh)
{
    const int NX = B_ROWS * D_DIM;
    const int NW = D_DIM * D_DIM;
    const int total = NX + 3 * NW;
    int i = (blockIdx.x * 256 + threadIdx.x) * 4;
    int stride = gridDim.x * 256 * 4;
    for (; i < total; i += stride) {
        const float* in; half_t* out; int j;
        if (i < NX)               { in = x;  out = xh;  j = i; }
        else if (i < NX + NW)     { in = Wq; out = Wqh; j = i - NX; }
        else if (i < NX + 2 * NW) { in = Wk; out = Wkh; j = i - NX - NW; }
        else                      { in = Wv; out = Wvh; j = i - NX - 2 * NW; }
        float4 v = *(const float4*)&in[j];
        f16x4 o;
        o[0] = (half_t)v.x; o[1] = (half_t)v.y; o[2] = (half_t)v.z; o[3] = (half_t)v.w;
        *(f16x4*)&out[j] = o;
    }
}

// ---------------------------------------------------------------------------
// 256x256 NT GEMM core (round-5 structure, measured ~875 TF), 32x32x16 MFMA.
//   raw[i,j] = scale * sum_k A[i,k]*B[j,k]
// 512 threads = 8 waves (2Mx4N). LDS 128 KiB (2 dbuf x 2 halves x A,B).
// 2-barrier 4-phase K-loop with B-frag dedup; one counted vmcnt(4)/K-tile.
// Swizzle: 16B-slot ^= (row&7) on read; inverse-swizzled global source.
// EPI: 0 = +aux[col] bias, f16 out                       (Q/K projections)
//      3 = exp(raw-20) f16 out + per-block row partials -> aux2[zcol][row]
//          (LDS-scratch reduction, no shuffles/atomics)  (QK^T)
//      4 = f32 out of raw*aux[row]                       (PV, aux = 1/Z)
//      5 = +aux[col] bias, TRANSPOSED f16 out Out[col*ldc+row]  (V -> V^T)
// ---------------------------------------------------------------------------
template<int EPI>
__device__ __forceinline__ void gemm8_core(
    const half_t* __restrict__ A, const half_t* __restrict__ Bm,
    const float* __restrict__ aux, float* __restrict__ aux2, int zcol,
    void* __restrict__ Out,
    int lda, int ldb, int ldc, float scale,
    int row0, int col0, int ktile0, int nkt)
{
    __shared__ __align__(16) half_t smem[8 * 8192];   // As | Bs (and epilogue scratch)
    half_t* As = smem;
    half_t* Bs = smem + 4 * 8192;

    const int tid  = threadIdx.x;
    const int lane = tid & 63;
    const int wid  = tid >> 6;
    const int wr   = wid >> 2;     // 0..1  (M)
    const int wcn  = wid & 3;      // 0..3  (N)
    const int l31  = lane & 31;
    const int l32  = lane >> 5;

    // staging: linear LDS dest (tid*16), inverse-swizzled global source slot
    const int trow  = tid >> 3;                       // 0..63
    const int tslot = (tid & 7) ^ (trow & 7);
    const char* Apan[2] = { (const char*)(A + (size_t)row0 * lda),
                            (const char*)(A + (size_t)(row0 + 128) * lda) };
    const char* Bpan[2] = { (const char*)(Bm + (size_t)col0 * ldb),
                            (const char*)(Bm + (size_t)(col0 + 128) * ldb) };
    const size_t aoff[2] = { (size_t)trow * lda * 2 + (size_t)tslot * 16,
                             (size_t)(trow + 64) * lda * 2 + (size_t)tslot * 16 };
    const size_t boff[2] = { (size_t)trow * ldb * 2 + (size_t)tslot * 16,
                             (size_t)(trow + 64) * ldb * 2 + (size_t)tslot * 16 };
    const int dstb[2] = { tid * 16, 8192 + tid * 16 };

    auto stageA = [&](int h, int s, int buf) {
        char* d = (char*)(As + (buf * 2 + h) * 8192);
        const char* g = Apan[h] + (size_t)(ktile0 + s) * 128;
        gload_lds16(g + aoff[0], d + dstb[0]);
        gload_lds16(g + aoff[1], d + dstb[1]);
    };
    auto stageB = [&](int h, int s, int buf) {
        char* d = (char*)(Bs + (buf * 2 + h) * 8192);
        const char* g = Bpan[h] + (size_t)(ktile0 + s) * 128;
        gload_lds16(g + boff[0], d + dstb[0]);
        gload_lds16(g + boff[1], d + dstb[1]);
    };
    // swizzled fragment reads, 32x32 operand layout: row=lane&31, k=l32*8+j
    auto rdA = [&](int mm, int kc, const half_t* base) -> f16x8 {
        int rih  = wr * 64 + mm * 32 + l31;
        int byte = rih * 128 + (((kc * 2 + l32) ^ (rih & 7)) << 4);
        return *(const f16x8*)((const char*)base + byte);
    };
    auto rdB = [&](int kc, const half_t* base) -> f16x8 {
        int rih  = wcn * 32 + l31;
        int byte = rih * 128 + (((kc * 2 + l32) ^ (rih & 7)) << 4);
        return *(const f16x8*)((const char*)base + byte);
    };

    f32x16 acc[2][2][2] = {};   // [h][mm][nh]
    f16x8 af[2][4];             // A frags (current half), [mm][kc]
    f16x8 bfP[4], bfQ[4];       // B-half0 / B-half1 frags, [kc]

    // prologue: stage K-tile 0 fully + A0/B0 of tile 1; gate tile 0 (8 loads)
    {
        int s1 = (nkt > 1) ? 1 : 0;
        stageA(0, 0, 0); stageB(0, 0, 0); stageA(1, 0, 0); stageB(1, 0, 0);
        stageA(0, s1, 1); stageB(0, s1, 1);
    }
    asm volatile("s_waitcnt vmcnt(4)" ::: "memory");
    asm volatile("s_barrier" ::: "memory");

    for (int t = 0; t < nkt; ++t) {
        const int buf = t & 1;
        const half_t* A0 = As + (buf * 2 + 0) * 8192;
        const half_t* A1 = As + (buf * 2 + 1) * 8192;
        const half_t* B0 = Bs + (buf * 2 + 0) * 8192;
        const half_t* B1 = Bs + (buf * 2 + 1) * 8192;
        int t1  = t + 1; int t1s = (t1 < nkt) ? t1 : nkt - 1; int b1 = t1 & 1;
        int t2  = t + 2; int t2s = (t2 < nkt) ? t2 : nkt - 1;

        // ---- phase 1: (A-half0, B-half0) -> acc[0][*][0]
        #pragma unroll
        for (int mm = 0; mm < 2; ++mm)
            #pragma unroll
            for (int kc = 0; kc < 4; ++kc) af[mm][kc] = rdA(mm, kc, A0);
        #pragma unroll
        for (int kc = 0; kc < 4; ++kc) bfP[kc] = rdB(kc, B0);
        stageA(1, t1s, b1);
        asm volatile("s_barrier" ::: "memory");
        __builtin_amdgcn_s_setprio(1);
        #pragma unroll
        for (int kc = 0; kc < 4; ++kc)
            #pragma unroll
            for (int mm = 0; mm < 2; ++mm)
                acc[0][mm][0] = __builtin_amdgcn_mfma_f32_32x32x16_f16(af[mm][kc], bfP[kc], acc[0][mm][0], 0, 0, 0);
        __builtin_amdgcn_s_setprio(0);
        asm volatile("s_barrier" ::: "memory");

        // ---- phase 2: (A-half0, B-half1) -> acc[0][*][1]
        #pragma unroll
        for (int kc = 0; kc < 4; ++kc) bfQ[kc] = rdB(kc, B1);
        stageB(1, t1s, b1);
        asm volatile("s_barrier" ::: "memory");
        __builtin_amdgcn_s_setprio(1);
        #pragma unroll
        for (int kc = 0; kc < 4; ++kc)
            #pragma unroll
            for (int mm = 0; mm < 2; ++mm)
                acc[0][mm][1] = __builtin_amdgcn_mfma_f32_32x32x16_f16(af[mm][kc], bfQ[kc], acc[0][mm][1], 0, 0, 0);
        __builtin_amdgcn_s_setprio(0);
        asm volatile("s_barrier" ::: "memory");

        // ---- phase 3: (A-half1, B-half0) -> acc[1][*][0]  (af overwritten, bfP reused)
        #pragma unroll
        for (int mm = 0; mm < 2; ++mm)
            #pragma unroll
            for (int kc = 0; kc < 4; ++kc) af[mm][kc] = rdA(mm, kc, A1);
        stageA(0, t2s, buf);
        asm volatile("s_barrier" ::: "memory");
        __builtin_amdgcn_s_setprio(1);
        #pragma unroll
        for (int kc = 0; kc < 4; ++kc)
            #pragma unroll
            for (int mm = 0; mm < 2; ++mm)
                acc[1][mm][0] = __builtin_amdgcn_mfma_f32_32x32x16_f16(af[mm][kc], bfP[kc], acc[1][mm][0], 0, 0, 0);
        __builtin_amdgcn_s_setprio(0);
        asm volatile("s_barrier" ::: "memory");

        // ---- phase 4: (A-half1, B-half1) -> acc[1][*][1]  (no reads)
        stageB(0, t2s, buf);
        asm volatile("s_barrier" ::: "memory");
        __builtin_amdgcn_s_setprio(1);
        #pragma unroll
        for (int kc = 0; kc < 4; ++kc)
            #pragma unroll
            for (int mm = 0; mm < 2; ++mm)
                acc[1][mm][1] = __builtin_amdgcn_mfma_f32_32x32x16_f16(af[mm][kc], bfQ[kc], acc[1][mm][1], 0, 0, 0);
        __builtin_amdgcn_s_setprio(0);
        asm volatile("s_waitcnt vmcnt(4)" ::: "memory");   // counted gate: next tile landed
        asm volatile("s_barrier" ::: "memory");
    }

    // epilogue: 32x32 C/D layout: col = lane&31, row = (g&3) + 8*(g>>2) + 4*l32
    if (EPI == 3) {
        // exp-space E stores + per-block row sums via LDS scratch (smem is
        // reusable after draining the trailing stage loads).
        asm volatile("s_waitcnt vmcnt(0)" ::: "memory");
        asm volatile("s_barrier" ::: "memory");
        half_t* scratch = smem;                    // [256][136] f16 = 69.6 KB
        const int contrib = wcn * 32 + l31;
        #pragma unroll
        for (int h = 0; h < 2; ++h) {
            #pragma unroll
            for (int mm = 0; mm < 2; ++mm) {
                int rl0 = h * 128 + wr * 64 + mm * 32 + 4 * l32;
                #pragma unroll
                for (int g = 0; g < 16; ++g) {
                    int rl = rl0 + (g & 3) + 8 * (g >> 2);
                    float rs = 0.0f;
                    #pragma unroll
                    for (int nh = 0; nh < 2; ++nh) {
                        int gcol = col0 + nh * 128 + wcn * 32 + l31;
                        float e = __expf(acc[h][mm][nh][g] * scale - 20.0f);
                        rs += e;
                        ((half_t*)Out)[(size_t)(row0 + rl) * ldc + gcol] = (half_t)e;
                    }
                    scratch[rl * 136 + contrib] = (half_t)rs;
                }
            }
        }
        asm volatile("s_waitcnt lgkmcnt(0)" ::: "memory");
        asm volatile("s_barrier" ::: "memory");
        {
            int row  = tid >> 1;
            int half = tid & 1;
            const half_t* src = scratch + row * 136 + half * 64;
            float s = 0.0f;
            #pragma unroll
            for (int j = 0; j < 8; ++j) {
                f16x8 v = *(const f16x8*)&src[j * 8];
                #pragma unroll
                for (int tt = 0; tt < 8; ++tt) s += (float)v[tt];
            }
            s += __shfl_xor(s, 1);
            if (half == 0) aux2[(size_t)zcol * B_ROWS + row0 + row] = s;
        }
    } else if (EPI == 5) {
        // transposed f16 store: Out[col * ldc + row]  (row-quads -> f16x4)
        #pragma unroll
        for (int h = 0; h < 2; ++h) {
            #pragma unroll
            for (int mm = 0; mm < 2; ++mm) {
                int r0 = row0 + h * 128 + wr * 64 + mm * 32 + 4 * l32;
                #pragma unroll
                for (int nh = 0; nh < 2; ++nh) {
                    int gcol = col0 + nh * 128 + wcn * 32 + l31;
                    float badd = aux[gcol];
                    #pragma unroll
                    for (int q = 0; q < 4; ++q) {
                        f16x4 v4;
                        #pragma unroll
                        for (int j = 0; j < 4; ++j)
                            v4[j] = (half_t)(acc[h][mm][nh][4 * q + j] * scale + badd);
                        *(f16x4*)&((half_t*)Out)[(size_t)gcol * ldc + r0 + 8 * q] = v4;
                    }
                }
            }
        }
    } else {
        #pragma unroll
        for (int h = 0; h < 2; ++h) {
            #pragma unroll
            for (int mm = 0; mm < 2; ++mm) {
                int r0 = row0 + h * 128 + wr * 64 + mm * 32 + 4 * l32;
                #pragma unroll
                for (int nh = 0; nh < 2; ++nh) {
                    int gcol = col0 + nh * 128 + wcn * 32 + l31;
                    float badd = (EPI == 0) ? aux[gcol] : 0.0f;
                    #pragma unroll
                    for (int g = 0; g < 16; ++g) {
                        int row = r0 + (g & 3) + 8 * (g >> 2);
                        float v = acc[h][mm][nh][g] * scale + badd;
                        size_t idx = (size_t)row * ldc + gcol;
                        if (EPI == 4)      ((float*)Out)[idx] = v * aux[row];
                        else               ((half_t*)Out)[idx] = (half_t)v;
                    }
                }
            }
        }
    }
}

// wrapper. REMAP=1: 16x16 supertile + XCD-chunked 2x16 slabs (requires 32x32 grid).
// REMAP=0: plain XCD swizzle. zcol (for EPI=3 partial sums) = bx.
template<int EPI, int REMAP>
__global__ __launch_bounds__(512, 2)
void gemm8(const half_t* __restrict__ A, const half_t* __restrict__ Bm,
           const float* __restrict__ aux, float* __restrict__ aux2,
           void* __restrict__ Out,
           int lda, int ldb, int ldc, float scale, int nkt)
{
    int bx, by;
    if (REMAP) {
        int L = blockIdx.y * gridDim.x + blockIdx.x;   // 0..1023
        int s = L >> 8;            // supertile 0..3 (2x2 of 16x16)
        int u = L & 255;
        int xcd  = u & 7;
        int slot = u >> 3;         // 0..31 within XCD: 2 rows x 16 cols
        by = (s >> 1) * 16 + xcd * 2 + (slot >> 4);
        bx = (s & 1) * 16 + (slot & 15);
    } else {
        int nwg = gridDim.x * gridDim.y;
        int bid = blockIdx.y * gridDim.x + blockIdx.x;
        if ((nwg & 7) == 0) { int c = nwg >> 3; bid = (bid & 7) * c + (bid >> 3); }
        bx = bid % gridDim.x; by = bid / gridDim.x;
    }
    gemm8_core<EPI>(A, Bm, aux, aux2, bx, Out, lda, ldb, ldc, scale,
                    by * 256, bx * 256, 0, nkt);
}

// Q/K projections: z picks (W, b, Out)  [r4 mapping: direct blockIdx]
__global__ __launch_bounds__(512, 2)
void gemm8_qk(const half_t* __restrict__ xh,
              const half_t* __restrict__ Wq, const half_t* __restrict__ Wk,
              const float* __restrict__ bq, const float* __restrict__ bk,
              half_t* __restrict__ Q, half_t* __restrict__ K)
{
    int z = blockIdx.z;
    const half_t* W = z ? Wk : Wq;
    const float*  b = z ? bk : bq;
    half_t*       O = z ? K  : Q;
    gemm8_core<0>(xh, W, b, nullptr, 0, O, D_DIM, D_DIM, D_DIM, 1.0f,
                  blockIdx.y * 256, blockIdx.x * 256, 0, D_DIM / 64);
}

// V projection with fused transpose: writes Vt[col][row] (ldc = B_ROWS)
__global__ __launch_bounds__(512, 2)
void gemm8_v(const half_t* __restrict__ xh, const half_t* __restrict__ Wv,
             const float* __restrict__ bv, half_t* __restrict__ Vt)
{
    gemm8_core<5>(xh, Wv, bv, nullptr, 0, Vt, D_DIM, D_DIM, B_ROWS, 1.0f,
                  blockIdx.y * 256, blockIdx.x * 256, 0, D_DIM / 64);
}

// PV with split-K=2 [r4 mapping], plain stores of (E V^T)*Zinv[row] into
// part0 (=out) / part1; reduced by add_f32 afterwards.
__global__ __launch_bounds__(512, 2)
void gemm8_pv(const half_t* __restrict__ E, const half_t* __restrict__ Vt,
              const float* __restrict__ Zinv,
              float* __restrict__ part0, float* __restrict__ part1)
{
    int z = blockIdx.z;
    float* O = z ? part1 : part0;
    gemm8_core<4>(E, Vt, Zinv, nullptr, 0, O, B_ROWS, B_ROWS, D_DIM, 1.0f,
                  blockIdx.y * 256, blockIdx.x * 256, z * (B_ROWS / 128), B_ROWS / 128);
}

// Zinv[r] = 1 / sum_c Zpart[c][r]   (32 col-block partials per row)
__global__ __launch_bounds__(256)
void zreduce(const float* __restrict__ Zpart, float* __restrict__ Zinv, int nrow)
{
    int r = blockIdx.x * 256 + threadIdx.x;
    float s = 0.0f;
    #pragma unroll
    for (int c = 0; c < 32; ++c) s += Zpart[(size_t)c * nrow + r];
    Zinv[r] = 1.0f / s;
}

// out += a
__global__ __launch_bounds__(256)
void add_f32(const float* __restrict__ a, float* __restrict__ out, int n)
{
    int i = (blockIdx.x * 256 + threadIdx.x) * 4;
    int stride = gridDim.x * 256 * 4;
    for (; i < n; i += stride) {
        float4 x = *(const float4*)&out[i];
        float4 y = *(const float4*)&a[i];
        x.x += y.x; x.y += y.y; x.z += y.z; x.w += y.w;
        *(float4*)&out[i] = x;
    }
}

// ---------------------------------------------------------------------------
// launcher
// ---------------------------------------------------------------------------
extern "C" void kernel_launch(void* const* d_in, const int* in_sizes, int n_in,
                              void* d_out, int out_size, void* d_ws, size_t ws_size,
                              hipStream_t stream)
{
    const float* x  = (const float*)d_in[0];
    const float* Wq = (const float*)d_in[1];
    const float* bq = (const float*)d_in[2];
    const float* Wk = (const float*)d_in[3];
    const float* bk = (const float*)d_in[4];
    const float* Wv = (const float*)d_in[5];
    const float* bv = (const float*)d_in[6];
    float* out = (float*)d_out;

    const int Bb = B_ROWS, Dd = D_DIM;

    char* w = (char*)d_ws;
    size_t off = 0;
    auto carve = [&](size_t bytes) {
        void* p = w + off;
        off += (bytes + 255) & ~(size_t)255;
        return p;
    };
    half_t* xh  = (half_t*)carve((size_t)Bb * Dd * 2);
    half_t* Wqh = (half_t*)carve((size_t)Dd * Dd * 2);
    half_t* Wkh = (half_t*)carve((size_t)Dd * Dd * 2);
    half_t* Wvh = (half_t*)carve((size_t)Dd * Dd * 2);
    half_t* Qh  = (half_t*)carve((size_t)Bb * Dd * 2);
    half_t* Kh  = (half_t*)carve((size_t)Bb * Dd * 2);
    half_t* Vt  = (half_t*)carve((size_t)Bb * Dd * 2);   // V^T, written directly
    half_t* S   = (half_t*)carve((size_t)Bb * Bb * 2);   // exp-space E
    float*  Zp  = (float*)carve((size_t)32 * Bb * 4);     // per-colblock row sums
    float*  Z   = (float*)carve((size_t)Bb * 4);          // 1/rowsum
    float*  part1 = (float*)Qh;       // Qh+Kh dead after QK^T

    // 1) merged converts (one dispatch)
    cvt_all<<<2048, 256, 0, stream>>>(x, Wq, Wk, Wv, xh, Wqh, Wkh, Wvh);

    // 2) projections: Q,K (z-fused) + V with fused transpose
    dim3 gqk(Dd / 256, Bb / 256, 2);
    gemm8_qk<<<gqk, 512, 0, stream>>>(xh, Wqh, Wkh, bq, bk, Qh, Kh);
    dim3 gv(Dd / 256, Bb / 256);
    gemm8_v<<<gv, 512, 0, stream>>>(xh, Wvh, bv, Vt);

    // 3) E = exp(0.125*Q K^T - 20) + per-block row partials -> Zp  (supertile remap)
    dim3 gs(Bb / 256, Bb / 256);
    gemm8<3, 1><<<gs, 512, 0, stream>>>(Qh, Kh, nullptr, Zp, S, Dd, Dd, Bb, 0.125f, Dd / 64);

    // 4) Zinv = 1 / rowsum  (1 MB reduce)
    zreduce<<<Bb / 256, 256, 0, stream>>>(Zp, Z, Bb);

    // 5) O = (E Vt^T) * Zinv[row], split-K=2 (plain stores), then reduce partials
    dim3 gpv(Dd / 256, Bb / 256, 2);
    gemm8_pv<<<gpv, 512, 0, stream>>>(S, Vt, Z, out, part1);
    add_f32<<<2048, 256, 0, stream>>>(part1, out, Bb * Dd);
}